// Round 1
// baseline (2614.408 us; speedup 1.0000x reference)
//
#include <hip/hip_runtime.h>
#include <hip/hip_bf16.h>
#include <math.h>

#define B_  4
#define T_  2048
#define D_  1024
#define H_  16
#define HD_ 64
#define D3_ 3072

// ---------------------------------------------------------------------------
// Generic fp32 GEMM with bias: C[M][N] = A[M][K] @ W[K][N] + bias[N]
// 128x128 tile, BK=16, 256 threads, 8x8 micro-tile per thread (2x2 of 4x4).
// ---------------------------------------------------------------------------
#define BM 128
#define BN 128
#define BK 16

__global__ __launch_bounds__(256) void gemm_bias(
    const float* __restrict__ A, const float* __restrict__ W,
    const float* __restrict__ bias, float* __restrict__ C,
    int M, int N, int K) {
  __shared__ float As[BK][BM + 4];  // A stored transposed: As[k][m]
  __shared__ float Ws[BK][BN + 4];

  const int tid = threadIdx.x;
  const int tx = tid & 15;   // 0..15 -> column group
  const int ty = tid >> 4;   // 0..15 -> row group
  const int row0 = blockIdx.y * BM;
  const int col0 = blockIdx.x * BN;

  float acc[8][8];
#pragma unroll
  for (int i = 0; i < 8; ++i)
#pragma unroll
    for (int j = 0; j < 8; ++j) acc[i][j] = 0.f;

  for (int k0 = 0; k0 < K; k0 += BK) {
    __syncthreads();  // previous-iteration LDS reads done
#pragma unroll
    for (int i = 0; i < 2; ++i) {
      int lin = tid + i * 256;
      // A tile: 128 rows x 16 k, as 512 float4 (4 float4 per row along k)
      int ar = lin >> 2, ac = (lin & 3) * 4;
      float4 av = *(const float4*)(A + (size_t)(row0 + ar) * K + k0 + ac);
      As[ac + 0][ar] = av.x;
      As[ac + 1][ar] = av.y;
      As[ac + 2][ar] = av.z;
      As[ac + 3][ar] = av.w;
      // W tile: 16 rows x 128 cols, as 512 float4 (32 float4 per row)
      int wr = lin >> 5, wc = (lin & 31) * 4;
      *(float4*)&Ws[wr][wc] = *(const float4*)(W + (size_t)(k0 + wr) * N + col0 + wc);
    }
    __syncthreads();

#pragma unroll
    for (int kk = 0; kk < BK; ++kk) {
      float4 a0 = *(const float4*)&As[kk][ty * 4];
      float4 a1 = *(const float4*)&As[kk][64 + ty * 4];
      float4 w0 = *(const float4*)&Ws[kk][tx * 4];
      float4 w1 = *(const float4*)&Ws[kk][64 + tx * 4];
      float av[8] = {a0.x, a0.y, a0.z, a0.w, a1.x, a1.y, a1.z, a1.w};
      float wv[8] = {w0.x, w0.y, w0.z, w0.w, w1.x, w1.y, w1.z, w1.w};
#pragma unroll
      for (int mm = 0; mm < 8; ++mm)
#pragma unroll
        for (int nn = 0; nn < 8; ++nn)
          acc[mm][nn] = fmaf(av[mm], wv[nn], acc[mm][nn]);
    }
  }

  // epilogue: bias + store (float4 along n)
#pragma unroll
  for (int mm = 0; mm < 8; ++mm) {
    int row = row0 + (mm >> 2) * 64 + ty * 4 + (mm & 3);
#pragma unroll
    for (int ng = 0; ng < 2; ++ng) {
      int col = col0 + ng * 64 + tx * 4;
      float4 bv = *(const float4*)(bias + col);
      float4 res;
      res.x = acc[mm][ng * 4 + 0] + bv.x;
      res.y = acc[mm][ng * 4 + 1] + bv.y;
      res.z = acc[mm][ng * 4 + 2] + bv.z;
      res.w = acc[mm][ng * 4 + 3] + bv.w;
      *(float4*)(C + (size_t)row * N + col) = res;
    }
  }
}

// ---------------------------------------------------------------------------
// Causal flash attention, fp32. qkv layout: (B*T, 3D) rows; per (b,h):
//   Q[t][d] = qkv[(b*T+t)*3D +        h*64 + d]
//   K[t][d] = qkv[(b*T+t)*3D + 1024 + h*64 + d]
//   V[t][d] = qkv[(b*T+t)*3D + 2048 + h*64 + d]
// One 256-thread block handles 256 q rows for one (b,h); each thread owns
// one q row fully in registers. K/V staged in LDS in 64-key tiles.
// y layout: (B*T, D) with y[(b*T+t)*D + h*64 + d].
// ---------------------------------------------------------------------------
#define QBLK 256
#define KBLK 64

__global__ __launch_bounds__(256) void attn_fwd(
    const float* __restrict__ qkv, float* __restrict__ y) {
  const int bh = blockIdx.y;
  const int b = bh >> 4;
  const int h = bh & 15;
  const int qt = blockIdx.x;
  const int tid = threadIdx.x;
  const int qr = qt * QBLK + tid;  // this thread's global q row

  __shared__ float Kt[KBLK][68];
  __shared__ float Vt[KBLK][68];

  // load this thread's q row into registers
  float4 q[16];
  {
    const float4* qp = (const float4*)(qkv + (size_t)(b * T_ + qr) * D3_ + h * HD_);
#pragma unroll
    for (int i = 0; i < 16; ++i) q[i] = qp[i];
  }

  float4 o[16];
#pragma unroll
  for (int i = 0; i < 16; ++i) o[i] = make_float4(0.f, 0.f, 0.f, 0.f);
  float m = -INFINITY, l = 0.f;
  const float scale = 0.125f;  // 1/sqrt(64)

  const int ntiles = qt * (QBLK / KBLK) + (QBLK / KBLK);

  for (int kt = 0; kt < ntiles; ++kt) {
    __syncthreads();  // previous-iteration LDS reads done
    {
      int r0 = tid >> 4, jc = tid & 15;
#pragma unroll
      for (int i = 0; i < 4; ++i) {
        int r = r0 + i * 16;
        size_t rowbase = (size_t)(b * T_ + kt * KBLK + r) * D3_ + h * HD_;
        *(float4*)&Kt[r][jc * 4] = *(const float4*)(qkv + rowbase + 1024 + jc * 4);
        *(float4*)&Vt[r][jc * 4] = *(const float4*)(qkv + rowbase + 2048 + jc * 4);
      }
    }
    __syncthreads();

    if (kt * KBLK <= qr) {  // this thread has at least one valid key here
#pragma unroll 1
      for (int c = 0; c < 4; ++c) {  // chunks of 16 keys
        float s[16];
        float cmax = -INFINITY;
#pragma unroll 4
        for (int j = 0; j < 16; ++j) {
          int kj = c * 16 + j;
          const float4* kr = (const float4*)&Kt[kj][0];
          float s0 = 0.f, s1 = 0.f, s2 = 0.f, s3 = 0.f;
#pragma unroll
          for (int d = 0; d < 16; ++d) {
            float4 kv = kr[d];
            s0 = fmaf(q[d].x, kv.x, s0);
            s1 = fmaf(q[d].y, kv.y, s1);
            s2 = fmaf(q[d].z, kv.z, s2);
            s3 = fmaf(q[d].w, kv.w, s3);
          }
          float sj = (s0 + s1) + (s2 + s3);
          sj *= scale;
          int kg = kt * KBLK + kj;
          s[j] = (kg <= qr) ? sj : -INFINITY;
          cmax = fmaxf(cmax, s[j]);
        }
        if (cmax != -INFINITY) {
          float nm = fmaxf(m, cmax);
          float corr = __expf(m - nm);  // m=-inf -> 0
          l *= corr;
#pragma unroll
          for (int d = 0; d < 16; ++d) {
            o[d].x *= corr; o[d].y *= corr; o[d].z *= corr; o[d].w *= corr;
          }
          m = nm;
#pragma unroll 4
          for (int j = 0; j < 16; ++j) {
            int kj = c * 16 + j;
            float p = __expf(s[j] - nm);  // masked: exp(-inf)=0
            l += p;
            const float4* vr = (const float4*)&Vt[kj][0];
#pragma unroll
            for (int d = 0; d < 16; ++d) {
              float4 vv = vr[d];
              o[d].x = fmaf(p, vv.x, o[d].x);
              o[d].y = fmaf(p, vv.y, o[d].y);
              o[d].z = fmaf(p, vv.z, o[d].z);
              o[d].w = fmaf(p, vv.w, o[d].w);
            }
          }
        }
      }
    }
  }

  float inv = 1.f / l;
  float4* yp = (float4*)(y + (size_t)(b * T_ + qr) * D_ + h * HD_);
#pragma unroll
  for (int i = 0; i < 16; ++i) {
    float4 r = o[i];
    r.x *= inv; r.y *= inv; r.z *= inv; r.w *= inv;
    yp[i] = r;
  }
}

// ---------------------------------------------------------------------------
extern "C" void kernel_launch(void* const* d_in, const int* in_sizes, int n_in,
                              void* d_out, int out_size, void* d_ws, size_t ws_size,
                              hipStream_t stream) {
  const float* x      = (const float*)d_in[0];
  const float* w_attn = (const float*)d_in[1];
  const float* b_attn = (const float*)d_in[2];
  const float* w_proj = (const float*)d_in[3];
  const float* b_proj = (const float*)d_in[4];
  float* out = (float*)d_out;

  float* qkv = (float*)d_ws;                       // (B*T, 3D) = 96 MB
  float* y   = qkv + (size_t)(B_ * T_) * D3_;      // (B*T, D)  = 32 MB

  const int M = B_ * T_;  // 8192

  // 1) qkv = x @ w_attn + b_attn
  {
    dim3 grid(D3_ / BN, M / BM);
    gemm_bias<<<grid, 256, 0, stream>>>(x, w_attn, b_attn, qkv, M, D3_, D_);
  }
  // 2) y = causal_attention(qkv)
  {
    dim3 grid(T_ / QBLK, B_ * H_);
    attn_fwd<<<grid, 256, 0, stream>>>(qkv, y);
  }
  // 3) out = y @ w_proj + b_proj
  {
    dim3 grid(D_ / BN, M / BM);
    gemm_bias<<<grid, 256, 0, stream>>>(y, w_proj, b_proj, out, M, D_, D_);
  }
}

// Round 2
// 1006.308 us; speedup vs baseline: 2.5980x; 2.5980x over previous
//
#include <hip/hip_runtime.h>
#include <math.h>

typedef __bf16 bf16_t;
typedef __attribute__((ext_vector_type(8))) __bf16 bf16x8;
typedef __attribute__((ext_vector_type(4))) float f32x4;

#define B_  4
#define T_  2048
#define D_  1024
#define H_  16
#define HD_ 64
#define D3_ 3072

// ---------------------------------------------------------------------------
// fp32 GEMM with bias: C[M][N] = A[M][K] @ W[K][N] + bias[N]
// Output either fp32 or bf16 (template).
// ---------------------------------------------------------------------------
#define BM 128
#define BN 128
#define BK 16

template <bool BF16_OUT>
__global__ __launch_bounds__(256) void gemm_bias(
    const float* __restrict__ A, const float* __restrict__ W,
    const float* __restrict__ bias, void* __restrict__ Cv,
    int M, int N, int K) {
  __shared__ float As[BK][BM + 4];  // A stored transposed: As[k][m]
  __shared__ float Ws[BK][BN + 4];

  const int tid = threadIdx.x;
  const int tx = tid & 15;
  const int ty = tid >> 4;
  const int row0 = blockIdx.y * BM;
  const int col0 = blockIdx.x * BN;

  float acc[8][8];
#pragma unroll
  for (int i = 0; i < 8; ++i)
#pragma unroll
    for (int j = 0; j < 8; ++j) acc[i][j] = 0.f;

  for (int k0 = 0; k0 < K; k0 += BK) {
    __syncthreads();
#pragma unroll
    for (int i = 0; i < 2; ++i) {
      int lin = tid + i * 256;
      int ar = lin >> 2, ac = (lin & 3) * 4;
      float4 av = *(const float4*)(A + (size_t)(row0 + ar) * K + k0 + ac);
      As[ac + 0][ar] = av.x;
      As[ac + 1][ar] = av.y;
      As[ac + 2][ar] = av.z;
      As[ac + 3][ar] = av.w;
      int wr = lin >> 5, wc = (lin & 31) * 4;
      *(float4*)&Ws[wr][wc] = *(const float4*)(W + (size_t)(k0 + wr) * N + col0 + wc);
    }
    __syncthreads();

#pragma unroll
    for (int kk = 0; kk < BK; ++kk) {
      float4 a0 = *(const float4*)&As[kk][ty * 4];
      float4 a1 = *(const float4*)&As[kk][64 + ty * 4];
      float4 w0 = *(const float4*)&Ws[kk][tx * 4];
      float4 w1 = *(const float4*)&Ws[kk][64 + tx * 4];
      float av[8] = {a0.x, a0.y, a0.z, a0.w, a1.x, a1.y, a1.z, a1.w};
      float wv[8] = {w0.x, w0.y, w0.z, w0.w, w1.x, w1.y, w1.z, w1.w};
#pragma unroll
      for (int mm = 0; mm < 8; ++mm)
#pragma unroll
        for (int nn = 0; nn < 8; ++nn)
          acc[mm][nn] = fmaf(av[mm], wv[nn], acc[mm][nn]);
    }
  }

#pragma unroll
  for (int mm = 0; mm < 8; ++mm) {
    int row = row0 + (mm >> 2) * 64 + ty * 4 + (mm & 3);
#pragma unroll
    for (int ng = 0; ng < 2; ++ng) {
      int col = col0 + ng * 64 + tx * 4;
      float4 bv = *(const float4*)(bias + col);
      float4 res;
      res.x = acc[mm][ng * 4 + 0] + bv.x;
      res.y = acc[mm][ng * 4 + 1] + bv.y;
      res.z = acc[mm][ng * 4 + 2] + bv.z;
      res.w = acc[mm][ng * 4 + 3] + bv.w;
      if constexpr (BF16_OUT) {
        bf16_t* C = (bf16_t*)Cv;
        alignas(8) bf16_t r4[4] = {(bf16_t)res.x, (bf16_t)res.y,
                                   (bf16_t)res.z, (bf16_t)res.w};
        *(uint2*)(C + (size_t)row * N + col) = *(const uint2*)r4;
      } else {
        float* C = (float*)Cv;
        *(float4*)(C + (size_t)row * N + col) = res;
      }
    }
  }
}

// ---------------------------------------------------------------------------
// Transpose V out of qkv_bf into Vg[bh][d][t] (bf16), so attention's PV
// B-fragment is a contiguous ds_read_b128 from LDS.
// Grid: (T/64, B*H). Wave-coalesced scalar reads (lane = d), 16B writes.
// ---------------------------------------------------------------------------
__global__ __launch_bounds__(256) void transpose_v(
    const bf16_t* __restrict__ qkv, bf16_t* __restrict__ Vg) {
  const int bh = blockIdx.y;
  const int b = bh >> 4, h = bh & 15;
  const int t0 = blockIdx.x * 64;
  const int tid = threadIdx.x;
  const int d = tid & 63;
  const int w = tid >> 6;  // t-subgroup of 16
  alignas(16) bf16_t tmp[16];
#pragma unroll
  for (int j = 0; j < 16; ++j) {
    int t = t0 + w * 16 + j;
    tmp[j] = qkv[(size_t)(b * T_ + t) * D3_ + 2 * D_ + h * HD_ + d];
  }
  bf16_t* dst = Vg + (size_t)(bh * HD_ + d) * T_ + t0 + w * 16;
  *(uint4*)(dst) = *(const uint4*)(tmp);
  *(uint4*)(dst + 8) = *(const uint4*)(tmp + 8);
}

// ---------------------------------------------------------------------------
// Causal flash attention with bf16 MFMA (16x16x32).
// Block = 256 threads = 4 waves, QBLK=128 q rows of one (b,h); wave w owns
// rows [Q0+32w, Q0+32w+32) as 2 row-groups of 16. K tiles (64 keys) staged
// row-major in LDS (72-pitch), V^T staged from Vg. P via per-wave LDS.
// Fragment layouts (16x16x32): A row=l&15, k=(l>>4)*8+j; B col=l&15, same k;
// C/D col=l&15, row=(l>>4)*4+reg  [guide-verified].
// ---------------------------------------------------------------------------
#define QBLK 128
#define KBLK 64

__global__ __launch_bounds__(256) void attn_fwd_mfma(
    const bf16_t* __restrict__ qkv, const bf16_t* __restrict__ Vg,
    float* __restrict__ y) {
  const int bh = blockIdx.y, b = bh >> 4, h = bh & 15;
  const int Q0 = blockIdx.x * QBLK;
  const int tid = threadIdx.x;
  const int w = tid >> 6, l = tid & 63;
  const int l15 = l & 15, lhi = l >> 4;

  __shared__ __align__(16) bf16_t K_lds[KBLK][72];
  __shared__ __align__(16) bf16_t Vt_lds[HD_][72];
  __shared__ __align__(16) bf16_t P_lds[4][16][72];

  // Q fragments (global -> regs, once)
  bf16x8 qf[2][2];
#pragma unroll
  for (int g = 0; g < 2; ++g) {
    int q = Q0 + w * 32 + g * 16 + l15;
#pragma unroll
    for (int c = 0; c < 2; ++c) {
      const bf16_t* p = qkv + (size_t)(b * T_ + q) * D3_ + h * HD_ + c * 32 + lhi * 8;
      qf[g][c] = *(const bf16x8*)p;
    }
  }

  f32x4 accO[2][4];
#pragma unroll
  for (int g = 0; g < 2; ++g)
#pragma unroll
    for (int dg = 0; dg < 4; ++dg) accO[g][dg] = (f32x4){0.f, 0.f, 0.f, 0.f};
  float m[2][4], lsum[2][4];
#pragma unroll
  for (int g = 0; g < 2; ++g)
#pragma unroll
    for (int r = 0; r < 4; ++r) { m[g][r] = -INFINITY; lsum[g][r] = 0.f; }

  const int ntiles = Q0 / KBLK + 2;
  const int qw_hi = Q0 + w * 32 + 31;

  for (int kt = 0; kt < ntiles; ++kt) {
    __syncthreads();
    // stage K tile (row-major) and V^T tile
#pragma unroll
    for (int i = 0; i < 2; ++i) {
      int lin = tid + i * 256;
      int r = lin >> 3, c = lin & 7;
      const bf16_t* ksrc =
          qkv + (size_t)(b * T_ + kt * KBLK + r) * D3_ + D_ + h * HD_ + c * 8;
      *(uint4*)&K_lds[r][c * 8] = *(const uint4*)ksrc;
      const bf16_t* vsrc = Vg + (size_t)(bh * HD_ + r) * T_ + kt * KBLK + c * 8;
      *(uint4*)&Vt_lds[r][c * 8] = *(const uint4*)vsrc;
    }
    __syncthreads();

    if (kt * KBLK > qw_hi) continue;  // wave entirely below diagonal

#pragma unroll
    for (int g = 0; g < 2; ++g) {
      const int qg = Q0 + w * 32 + g * 16;  // min q row of this group
      if (kt * KBLK > qg + 15) continue;    // fully masked for this group

      // ---- QK^T: S (16q x 64k) ----
      f32x4 s[4];
#pragma unroll
      for (int n = 0; n < 4; ++n) s[n] = (f32x4){0.f, 0.f, 0.f, 0.f};
#pragma unroll
      for (int c = 0; c < 2; ++c) {
#pragma unroll
        for (int n = 0; n < 4; ++n) {
          bf16x8 kf = *(const bf16x8*)&K_lds[n * 16 + l15][c * 32 + lhi * 8];
          s[n] = __builtin_amdgcn_mfma_f32_16x16x32_bf16(qf[g][c], kf, s[n], 0, 0, 0);
        }
      }

      // ---- scale + causal mask ----
      float sv[4][4];
      const bool needmask = (kt * KBLK + KBLK - 1 > qg);
#pragma unroll
      for (int n = 0; n < 4; ++n)
#pragma unroll
        for (int r = 0; r < 4; ++r) sv[n][r] = s[n][r] * 0.125f;
      if (needmask) {
#pragma unroll
        for (int n = 0; n < 4; ++n) {
          int kg = kt * KBLK + n * 16 + l15;
#pragma unroll
          for (int r = 0; r < 4; ++r) {
            int q = qg + lhi * 4 + r;
            if (kg > q) sv[n][r] = -INFINITY;
          }
        }
      }

      // ---- online softmax (row reduce across 16 lanes) ----
      float mr[4];
#pragma unroll
      for (int r = 0; r < 4; ++r)
        mr[r] = fmaxf(fmaxf(sv[0][r], sv[1][r]), fmaxf(sv[2][r], sv[3][r]));
#pragma unroll
      for (int off = 1; off < 16; off <<= 1)
#pragma unroll
        for (int r = 0; r < 4; ++r) mr[r] = fmaxf(mr[r], __shfl_xor(mr[r], off));

      float corr[4], mn[4];
#pragma unroll
      for (int r = 0; r < 4; ++r) {
        mn[r] = fmaxf(m[g][r], mr[r]);
        corr[r] = __expf(m[g][r] - mn[r]);  // m=-inf -> 0
        m[g][r] = mn[r];
      }

      float rs[4] = {0.f, 0.f, 0.f, 0.f};
#pragma unroll
      for (int n = 0; n < 4; ++n)
#pragma unroll
        for (int r = 0; r < 4; ++r) {
          float p = __expf(sv[n][r] - mn[r]);  // masked -> 0
          sv[n][r] = p;
          rs[r] += p;
        }
#pragma unroll
      for (int off = 1; off < 16; off <<= 1)
#pragma unroll
        for (int r = 0; r < 4; ++r) rs[r] += __shfl_xor(rs[r], off);
#pragma unroll
      for (int r = 0; r < 4; ++r) lsum[g][r] = lsum[g][r] * corr[r] + rs[r];

      // rescale O accumulators
#pragma unroll
      for (int dg = 0; dg < 4; ++dg)
#pragma unroll
        for (int r = 0; r < 4; ++r) accO[g][dg][r] *= corr[r];

      // ---- P -> LDS (C-layout scatter), then PV ----
#pragma unroll
      for (int n = 0; n < 4; ++n)
#pragma unroll
        for (int r = 0; r < 4; ++r)
          P_lds[w][lhi * 4 + r][n * 16 + l15] = (bf16_t)sv[n][r];

#pragma unroll
      for (int c2 = 0; c2 < 2; ++c2) {
        bf16x8 pf = *(const bf16x8*)&P_lds[w][l15][c2 * 32 + lhi * 8];
#pragma unroll
        for (int dg = 0; dg < 4; ++dg) {
          bf16x8 vf = *(const bf16x8*)&Vt_lds[dg * 16 + l15][c2 * 32 + lhi * 8];
          accO[g][dg] =
              __builtin_amdgcn_mfma_f32_16x16x32_bf16(pf, vf, accO[g][dg], 0, 0, 0);
        }
      }
    }
  }

  // epilogue: O / l -> y (fp32)
#pragma unroll
  for (int g = 0; g < 2; ++g)
#pragma unroll
    for (int r = 0; r < 4; ++r) {
      float inv = 1.f / lsum[g][r];
      int q = Q0 + w * 32 + g * 16 + lhi * 4 + r;
      float* yr = y + (size_t)(b * T_ + q) * D_ + h * HD_ + l15;
#pragma unroll
      for (int dg = 0; dg < 4; ++dg) yr[dg * 16] = accO[g][dg][r] * inv;
    }
}

// ---------------------------------------------------------------------------
extern "C" void kernel_launch(void* const* d_in, const int* in_sizes, int n_in,
                              void* d_out, int out_size, void* d_ws, size_t ws_size,
                              hipStream_t stream) {
  const float* x      = (const float*)d_in[0];
  const float* w_attn = (const float*)d_in[1];
  const float* b_attn = (const float*)d_in[2];
  const float* w_proj = (const float*)d_in[3];
  const float* b_proj = (const float*)d_in[4];
  float* out = (float*)d_out;

  bf16_t* qkv_bf = (bf16_t*)d_ws;                          // 48 MB
  bf16_t* Vg = qkv_bf + (size_t)(B_ * T_) * D3_;           // 16 MB
  float* y = (float*)(Vg + (size_t)(B_ * H_) * HD_ * T_);  // 32 MB

  const int M = B_ * T_;  // 8192

  // 1) qkv(bf16) = x @ w_attn + b_attn   (fp32 compute)
  gemm_bias<true><<<dim3(D3_ / BN, M / BM), 256, 0, stream>>>(
      x, w_attn, b_attn, qkv_bf, M, D3_, D_);
  // 2) Vg[bh][d][t] = V^T
  transpose_v<<<dim3(T_ / 64, B_ * H_), 256, 0, stream>>>(qkv_bf, Vg);
  // 3) y = causal_attention(qkv)  (bf16 MFMA)
  attn_fwd_mfma<<<dim3(T_ / QBLK, B_ * H_), 256, 0, stream>>>(qkv_bf, Vg, y);
  // 4) out = y @ w_proj + b_proj  (fp32)
  gemm_bias<false><<<dim3(D_ / BN, M / BM), 256, 0, stream>>>(
      y, w_proj, b_proj, out, M, D_, D_);
}

// Round 3
// 362.480 us; speedup vs baseline: 7.2126x; 2.7762x over previous
//
#include <hip/hip_runtime.h>
#include <math.h>

typedef __bf16 bf16_t;
typedef __attribute__((ext_vector_type(8))) __bf16 bf16x8;
typedef __attribute__((ext_vector_type(4))) float f32x4;

#define B_  4
#define T_  2048
#define D_  1024
#define H_  16
#define HD_ 64
#define D3_ 3072

// ---------------------------------------------------------------------------
// fp32 -> bf16 elementwise convert (vectorized)
// ---------------------------------------------------------------------------
__global__ __launch_bounds__(256) void convert_bf16(
    const float* __restrict__ in, bf16_t* __restrict__ out, int n4) {
  int idx = blockIdx.x * 256 + threadIdx.x;
  int stride = gridDim.x * 256;
  for (int i = idx; i < n4; i += stride) {
    float4 v = ((const float4*)in)[i];
    alignas(8) bf16_t o4[4] = {(bf16_t)v.x, (bf16_t)v.y, (bf16_t)v.z, (bf16_t)v.w};
    ((uint2*)out)[i] = *(const uint2*)o4;
  }
}

// ---------------------------------------------------------------------------
// W (K x N fp32) -> Wt (N x K bf16), tiled 64x64 transpose through LDS.
// ---------------------------------------------------------------------------
__global__ __launch_bounds__(256) void transpose_convert(
    const float* __restrict__ W, bf16_t* __restrict__ Wt, int K, int N) {
  __shared__ float tile[64][65];
  const int k0 = blockIdx.x * 64, n0 = blockIdx.y * 64;
  const int tid = threadIdx.x;
  const int r = tid >> 4, c4 = (tid & 15) * 4;
#pragma unroll
  for (int i = 0; i < 4; ++i) {
    float4 v = *(const float4*)(W + (size_t)(k0 + r + i * 16) * N + n0 + c4);
    tile[r + i * 16][c4 + 0] = v.x;
    tile[r + i * 16][c4 + 1] = v.y;
    tile[r + i * 16][c4 + 2] = v.z;
    tile[r + i * 16][c4 + 3] = v.w;
  }
  __syncthreads();
#pragma unroll
  for (int i = 0; i < 4; ++i) {
    int n = r + i * 16;
    alignas(8) bf16_t o4[4];
#pragma unroll
    for (int j = 0; j < 4; ++j) o4[j] = (bf16_t)tile[c4 + j][n];
    *(uint2*)(Wt + (size_t)(n0 + n) * K + k0 + c4) = *(const uint2*)o4;
  }
}

// ---------------------------------------------------------------------------
// bf16 MFMA GEMM: C[M][N] = A[M][K] @ Bt[N][K]^T + bias[N]
// m97 structure: 128x128 tile, BK=32, 256 thr / 4 waves (2x2 of 64x64),
// global_load_lds width-16 staging, chunk-XOR LDS swizzle (T2; source-side
// pre-swizzle + swizzled ds_read, linear LDS dest — rule #21).
// ---------------------------------------------------------------------------
#define GBM 128
#define GBN 128
#define GBK 32

__device__ __forceinline__ void load_lds16(const bf16_t* g, char* lds) {
  __builtin_amdgcn_global_load_lds(
      (const __attribute__((address_space(1))) void*)g,
      (__attribute__((address_space(3))) void*)lds, 16, 0, 0);
}

template <bool BF16_OUT>
__global__ __launch_bounds__(256) void gemm_bt_mfma(
    const bf16_t* __restrict__ A, const bf16_t* __restrict__ Bt,
    const float* __restrict__ bias, void* __restrict__ Cv,
    int M, int N, int K) {
  __shared__ __align__(16) bf16_t Asl[GBM * GBK];  // 8 KB (64B rows, 4 chunks)
  __shared__ __align__(16) bf16_t Bsl[GBN * GBK];  // 8 KB

  const int tid = threadIdx.x;
  const int w = tid >> 6, l = tid & 63;
  const int l15 = l & 15, lhi = l >> 4;
  const int row0 = blockIdx.y * GBM, col0 = blockIdx.x * GBN;
  const int wr = (w >> 1) * 64, wc = (w & 1) * 64;

  // staging: thread tid covers dest (row = issue*64 + tid/4, phys chunk tid&3)
  const int srow = tid >> 2;
  const int sf = (srow & 3) ^ ((srow >> 2) & 3);
  const int slog = (tid & 3) ^ sf;  // logical k-chunk this lane fetches
  // frag read: physical chunk for logical chunk lhi at row (..+l15)
  const int rf = (l15 & 3) ^ ((l15 >> 2) & 3);
  const int rchunk = lhi ^ rf;

  f32x4 acc[4][4];
#pragma unroll
  for (int i = 0; i < 4; ++i)
#pragma unroll
    for (int j = 0; j < 4; ++j) acc[i][j] = (f32x4){0.f, 0.f, 0.f, 0.f};

  const bf16_t* Abase = A + (size_t)row0 * K;
  const bf16_t* Bbase = Bt + (size_t)col0 * K;

  for (int k0 = 0; k0 < K; k0 += GBK) {
    __syncthreads();
#pragma unroll
    for (int issue = 0; issue < 2; ++issue) {
      const bf16_t* ga = Abase + (size_t)(issue * 64 + srow) * K + k0 + slog * 8;
      load_lds16(ga, (char*)Asl + issue * 4096 + w * 1024);
      const bf16_t* gb = Bbase + (size_t)(issue * 64 + srow) * K + k0 + slog * 8;
      load_lds16(gb, (char*)Bsl + issue * 4096 + w * 1024);
    }
    __syncthreads();  // drains vmcnt(0) before barrier

    bf16x8 af[4], bf[4];
#pragma unroll
    for (int i = 0; i < 4; ++i)
      af[i] = *(const bf16x8*)&Asl[(wr + i * 16 + l15) * GBK + rchunk * 8];
#pragma unroll
    for (int j = 0; j < 4; ++j)
      bf[j] = *(const bf16x8*)&Bsl[(wc + j * 16 + l15) * GBK + rchunk * 8];
#pragma unroll
    for (int i = 0; i < 4; ++i)
#pragma unroll
      for (int j = 0; j < 4; ++j)
        acc[i][j] =
            __builtin_amdgcn_mfma_f32_16x16x32_bf16(af[i], bf[j], acc[i][j], 0, 0, 0);
  }

  // epilogue: C/D layout col=l&15, row=(l>>4)*4+reg
#pragma unroll
  for (int j = 0; j < 4; ++j) {
    int colr = col0 + wc + j * 16 + l15;
    float bv = bias[colr];
#pragma unroll
    for (int i = 0; i < 4; ++i) {
#pragma unroll
      for (int r = 0; r < 4; ++r) {
        int rowr = row0 + wr + i * 16 + lhi * 4 + r;
        float val = acc[i][j][r] + bv;
        if constexpr (BF16_OUT)
          ((bf16_t*)Cv)[(size_t)rowr * N + colr] = (bf16_t)val;
        else
          ((float*)Cv)[(size_t)rowr * N + colr] = val;
      }
    }
  }
}

// ---------------------------------------------------------------------------
// Transpose V out of qkv_bf into Vg[bh][d][t] (bf16).
// ---------------------------------------------------------------------------
__global__ __launch_bounds__(256) void transpose_v(
    const bf16_t* __restrict__ qkv, bf16_t* __restrict__ Vg) {
  const int bh = blockIdx.y;
  const int b = bh >> 4, h = bh & 15;
  const int t0 = blockIdx.x * 64;
  const int tid = threadIdx.x;
  const int d = tid & 63;
  const int w = tid >> 6;
  alignas(16) bf16_t tmp[16];
#pragma unroll
  for (int j = 0; j < 16; ++j) {
    int t = t0 + w * 16 + j;
    tmp[j] = qkv[(size_t)(b * T_ + t) * D3_ + 2 * D_ + h * HD_ + d];
  }
  bf16_t* dst = Vg + (size_t)(bh * HD_ + d) * T_ + t0 + w * 16;
  *(uint4*)(dst) = *(const uint4*)(tmp);
  *(uint4*)(dst + 8) = *(const uint4*)(tmp + 8);
}

// ---------------------------------------------------------------------------
// Causal flash attention with bf16 MFMA (16x16x32). Unchanged from R1 except
// y is now written in bf16 (feeds the bf16 proj GEMM).
// ---------------------------------------------------------------------------
#define QBLK 128
#define KBLK 64

__global__ __launch_bounds__(256) void attn_fwd_mfma(
    const bf16_t* __restrict__ qkv, const bf16_t* __restrict__ Vg,
    bf16_t* __restrict__ y) {
  const int bh = blockIdx.y, b = bh >> 4, h = bh & 15;
  const int Q0 = blockIdx.x * QBLK;
  const int tid = threadIdx.x;
  const int w = tid >> 6, l = tid & 63;
  const int l15 = l & 15, lhi = l >> 4;

  __shared__ __align__(16) bf16_t K_lds[KBLK][72];
  __shared__ __align__(16) bf16_t Vt_lds[HD_][72];
  __shared__ __align__(16) bf16_t P_lds[4][16][72];

  bf16x8 qf[2][2];
#pragma unroll
  for (int g = 0; g < 2; ++g) {
    int q = Q0 + w * 32 + g * 16 + l15;
#pragma unroll
    for (int c = 0; c < 2; ++c) {
      const bf16_t* p = qkv + (size_t)(b * T_ + q) * D3_ + h * HD_ + c * 32 + lhi * 8;
      qf[g][c] = *(const bf16x8*)p;
    }
  }

  f32x4 accO[2][4];
#pragma unroll
  for (int g = 0; g < 2; ++g)
#pragma unroll
    for (int dg = 0; dg < 4; ++dg) accO[g][dg] = (f32x4){0.f, 0.f, 0.f, 0.f};
  float m[2][4], lsum[2][4];
#pragma unroll
  for (int g = 0; g < 2; ++g)
#pragma unroll
    for (int r = 0; r < 4; ++r) { m[g][r] = -INFINITY; lsum[g][r] = 0.f; }

  const int ntiles = Q0 / KBLK + 2;
  const int qw_hi = Q0 + w * 32 + 31;

  for (int kt = 0; kt < ntiles; ++kt) {
    __syncthreads();
#pragma unroll
    for (int i = 0; i < 2; ++i) {
      int lin = tid + i * 256;
      int r = lin >> 3, c = lin & 7;
      const bf16_t* ksrc =
          qkv + (size_t)(b * T_ + kt * KBLK + r) * D3_ + D_ + h * HD_ + c * 8;
      *(uint4*)&K_lds[r][c * 8] = *(const uint4*)ksrc;
      const bf16_t* vsrc = Vg + (size_t)(bh * HD_ + r) * T_ + kt * KBLK + c * 8;
      *(uint4*)&Vt_lds[r][c * 8] = *(const uint4*)vsrc;
    }
    __syncthreads();

    if (kt * KBLK > qw_hi) continue;

#pragma unroll
    for (int g = 0; g < 2; ++g) {
      const int qg = Q0 + w * 32 + g * 16;
      if (kt * KBLK > qg + 15) continue;

      f32x4 s[4];
#pragma unroll
      for (int n = 0; n < 4; ++n) s[n] = (f32x4){0.f, 0.f, 0.f, 0.f};
#pragma unroll
      for (int c = 0; c < 2; ++c) {
#pragma unroll
        for (int n = 0; n < 4; ++n) {
          bf16x8 kf = *(const bf16x8*)&K_lds[n * 16 + l15][c * 32 + lhi * 8];
          s[n] = __builtin_amdgcn_mfma_f32_16x16x32_bf16(qf[g][c], kf, s[n], 0, 0, 0);
        }
      }

      float sv[4][4];
      const bool needmask = (kt * KBLK + KBLK - 1 > qg);
#pragma unroll
      for (int n = 0; n < 4; ++n)
#pragma unroll
        for (int r = 0; r < 4; ++r) sv[n][r] = s[n][r] * 0.125f;
      if (needmask) {
#pragma unroll
        for (int n = 0; n < 4; ++n) {
          int kg = kt * KBLK + n * 16 + l15;
#pragma unroll
          for (int r = 0; r < 4; ++r) {
            int q = qg + lhi * 4 + r;
            if (kg > q) sv[n][r] = -INFINITY;
          }
        }
      }

      float mr[4];
#pragma unroll
      for (int r = 0; r < 4; ++r)
        mr[r] = fmaxf(fmaxf(sv[0][r], sv[1][r]), fmaxf(sv[2][r], sv[3][r]));
#pragma unroll
      for (int off = 1; off < 16; off <<= 1)
#pragma unroll
        for (int r = 0; r < 4; ++r) mr[r] = fmaxf(mr[r], __shfl_xor(mr[r], off));

      float corr[4], mn[4];
#pragma unroll
      for (int r = 0; r < 4; ++r) {
        mn[r] = fmaxf(m[g][r], mr[r]);
        corr[r] = __expf(m[g][r] - mn[r]);
        m[g][r] = mn[r];
      }

      float rs[4] = {0.f, 0.f, 0.f, 0.f};
#pragma unroll
      for (int n = 0; n < 4; ++n)
#pragma unroll
        for (int r = 0; r < 4; ++r) {
          float p = __expf(sv[n][r] - mn[r]);
          sv[n][r] = p;
          rs[r] += p;
        }
#pragma unroll
      for (int off = 1; off < 16; off <<= 1)
#pragma unroll
        for (int r = 0; r < 4; ++r) rs[r] += __shfl_xor(rs[r], off);
#pragma unroll
      for (int r = 0; r < 4; ++r) lsum[g][r] = lsum[g][r] * corr[r] + rs[r];

#pragma unroll
      for (int dg = 0; dg < 4; ++dg)
#pragma unroll
        for (int r = 0; r < 4; ++r) accO[g][dg][r] *= corr[r];

#pragma unroll
      for (int n = 0; n < 4; ++n)
#pragma unroll
        for (int r = 0; r < 4; ++r)
          P_lds[w][lhi * 4 + r][n * 16 + l15] = (bf16_t)sv[n][r];

#pragma unroll
      for (int c2 = 0; c2 < 2; ++c2) {
        bf16x8 pf = *(const bf16x8*)&P_lds[w][l15][c2 * 32 + lhi * 8];
#pragma unroll
        for (int dg = 0; dg < 4; ++dg) {
          bf16x8 vf = *(const bf16x8*)&Vt_lds[dg * 16 + l15][c2 * 32 + lhi * 8];
          accO[g][dg] =
              __builtin_amdgcn_mfma_f32_16x16x32_bf16(pf, vf, accO[g][dg], 0, 0, 0);
        }
      }
    }
  }

#pragma unroll
  for (int g = 0; g < 2; ++g)
#pragma unroll
    for (int r = 0; r < 4; ++r) {
      float inv = 1.f / lsum[g][r];
      int q = Q0 + w * 32 + g * 16 + lhi * 4 + r;
      bf16_t* yr = y + (size_t)(b * T_ + q) * D_ + h * HD_ + l15;
#pragma unroll
      for (int dg = 0; dg < 4; ++dg) yr[dg * 16] = (bf16_t)(accO[g][dg][r] * inv);
    }
}

// ---------------------------------------------------------------------------
extern "C" void kernel_launch(void* const* d_in, const int* in_sizes, int n_in,
                              void* d_out, int out_size, void* d_ws, size_t ws_size,
                              hipStream_t stream) {
  const float* x      = (const float*)d_in[0];
  const float* w_attn = (const float*)d_in[1];
  const float* b_attn = (const float*)d_in[2];
  const float* w_proj = (const float*)d_in[3];
  const float* b_proj = (const float*)d_in[4];
  float* out = (float*)d_out;

  const int M = B_ * T_;  // 8192

  // ws layout (88 MB total):
  bf16_t* xb      = (bf16_t*)d_ws;                         // 16 MB (reused as y_bf)
  bf16_t* wattnT  = xb + (size_t)M * D_;                   // 6 MB  (3072 x 1024)
  bf16_t* wprojT  = wattnT + (size_t)D3_ * D_;             // 2 MB  (1024 x 1024)
  bf16_t* qkv_bf  = wprojT + (size_t)D_ * D_;              // 48 MB (8192 x 3072)
  bf16_t* Vg      = qkv_bf + (size_t)M * D3_;              // 16 MB (64 x 64 x 2048)
  bf16_t* y_bf    = xb;  // alias: xb dead after QKV GEMM

  // 1) convert x -> bf16
  convert_bf16<<<2048, 256, 0, stream>>>(x, xb, M * D_ / 4);
  // 2) transpose+convert weights
  transpose_convert<<<dim3(D_ / 64, D3_ / 64), 256, 0, stream>>>(w_attn, wattnT, D_, D3_);
  transpose_convert<<<dim3(D_ / 64, D_ / 64), 256, 0, stream>>>(w_proj, wprojT, D_, D_);
  // 3) qkv = xb @ wattnT^T + b_attn  (bf16 MFMA)
  gemm_bt_mfma<true><<<dim3(D3_ / GBN, M / GBM), 256, 0, stream>>>(
      xb, wattnT, b_attn, qkv_bf, M, D3_, D_);
  // 4) Vg = V^T
  transpose_v<<<dim3(T_ / 64, B_ * H_), 256, 0, stream>>>(qkv_bf, Vg);
  // 5) y = causal_attention(qkv)  -> bf16
  attn_fwd_mfma<<<dim3(T_ / QBLK, B_ * H_), 256, 0, stream>>>(qkv_bf, Vg, y_bf);
  // 6) out = y @ wprojT^T + b_proj  (fp32 out)
  gemm_bt_mfma<false><<<dim3(D_ / GBN, M / GBM), 256, 0, stream>>>(
      y_bf, wprojT, b_proj, out, M, D_, D_);
}

// Round 4
// 197.798 us; speedup vs baseline: 13.2175x; 1.8326x over previous
//
#include <hip/hip_runtime.h>
#include <math.h>

typedef __bf16 bf16_t;
typedef __attribute__((ext_vector_type(8))) __bf16 bf16x8;
typedef __attribute__((ext_vector_type(4))) float f32x4;

#define B_  4
#define T_  2048
#define D_  1024
#define H_  16
#define HD_ 64
#define D3_ 3072

__device__ __forceinline__ void load_lds16(const bf16_t* g, char* lds) {
  __builtin_amdgcn_global_load_lds(
      (const __attribute__((address_space(1))) void*)g,
      (__attribute__((address_space(3))) void*)lds, 16, 0, 0);
}

// ---------------------------------------------------------------------------
// fp32 -> bf16 elementwise convert (vectorized)
// ---------------------------------------------------------------------------
__global__ __launch_bounds__(256) void convert_bf16(
    const float* __restrict__ in, bf16_t* __restrict__ out, int n4) {
  int idx = blockIdx.x * 256 + threadIdx.x;
  int stride = gridDim.x * 256;
  for (int i = idx; i < n4; i += stride) {
    float4 v = ((const float4*)in)[i];
    alignas(8) bf16_t o4[4] = {(bf16_t)v.x, (bf16_t)v.y, (bf16_t)v.z, (bf16_t)v.w};
    ((uint2*)out)[i] = *(const uint2*)o4;
  }
}

// ---------------------------------------------------------------------------
// W (K x N fp32) -> Wt (N x K bf16), tiled 64x64 transpose through LDS.
// ---------------------------------------------------------------------------
__global__ __launch_bounds__(256) void transpose_convert(
    const float* __restrict__ W, bf16_t* __restrict__ Wt, int K, int N) {
  __shared__ float tile[64][65];
  const int k0 = blockIdx.x * 64, n0 = blockIdx.y * 64;
  const int tid = threadIdx.x;
  const int r = tid >> 4, c4 = (tid & 15) * 4;
#pragma unroll
  for (int i = 0; i < 4; ++i) {
    float4 v = *(const float4*)(W + (size_t)(k0 + r + i * 16) * N + n0 + c4);
    tile[r + i * 16][c4 + 0] = v.x;
    tile[r + i * 16][c4 + 1] = v.y;
    tile[r + i * 16][c4 + 2] = v.z;
    tile[r + i * 16][c4 + 3] = v.w;
  }
  __syncthreads();
#pragma unroll
  for (int i = 0; i < 4; ++i) {
    int n = r + i * 16;
    alignas(8) bf16_t o4[4];
#pragma unroll
    for (int j = 0; j < 4; ++j) o4[j] = (bf16_t)tile[c4 + j][n];
    *(uint2*)(Wt + (size_t)(n0 + n) * K + k0 + c4) = *(const uint2*)o4;
  }
}

// ---------------------------------------------------------------------------
// bf16 MFMA GEMM: C[M][N] = A[M][K] @ Bt[N][K]^T + bias[N]  (unchanged R3)
// ---------------------------------------------------------------------------
#define GBM 128
#define GBN 128
#define GBK 32

template <bool BF16_OUT>
__global__ __launch_bounds__(256) void gemm_bt_mfma(
    const bf16_t* __restrict__ A, const bf16_t* __restrict__ Bt,
    const float* __restrict__ bias, void* __restrict__ Cv,
    int M, int N, int K) {
  __shared__ __align__(16) bf16_t Asl[GBM * GBK];
  __shared__ __align__(16) bf16_t Bsl[GBN * GBK];

  const int tid = threadIdx.x;
  const int w = tid >> 6, l = tid & 63;
  const int l15 = l & 15, lhi = l >> 4;
  const int row0 = blockIdx.y * GBM, col0 = blockIdx.x * GBN;
  const int wr = (w >> 1) * 64, wc = (w & 1) * 64;

  const int srow = tid >> 2;
  const int sf = (srow & 3) ^ ((srow >> 2) & 3);
  const int slog = (tid & 3) ^ sf;
  const int rf = (l15 & 3) ^ ((l15 >> 2) & 3);
  const int rchunk = lhi ^ rf;

  f32x4 acc[4][4];
#pragma unroll
  for (int i = 0; i < 4; ++i)
#pragma unroll
    for (int j = 0; j < 4; ++j) acc[i][j] = (f32x4){0.f, 0.f, 0.f, 0.f};

  const bf16_t* Abase = A + (size_t)row0 * K;
  const bf16_t* Bbase = Bt + (size_t)col0 * K;

  for (int k0 = 0; k0 < K; k0 += GBK) {
    __syncthreads();
#pragma unroll
    for (int issue = 0; issue < 2; ++issue) {
      const bf16_t* ga = Abase + (size_t)(issue * 64 + srow) * K + k0 + slog * 8;
      load_lds16(ga, (char*)Asl + issue * 4096 + w * 1024);
      const bf16_t* gb = Bbase + (size_t)(issue * 64 + srow) * K + k0 + slog * 8;
      load_lds16(gb, (char*)Bsl + issue * 4096 + w * 1024);
    }
    __syncthreads();

    bf16x8 af[4], bf[4];
#pragma unroll
    for (int i = 0; i < 4; ++i)
      af[i] = *(const bf16x8*)&Asl[(wr + i * 16 + l15) * GBK + rchunk * 8];
#pragma unroll
    for (int j = 0; j < 4; ++j)
      bf[j] = *(const bf16x8*)&Bsl[(wc + j * 16 + l15) * GBK + rchunk * 8];
#pragma unroll
    for (int i = 0; i < 4; ++i)
#pragma unroll
      for (int j = 0; j < 4; ++j)
        acc[i][j] =
            __builtin_amdgcn_mfma_f32_16x16x32_bf16(af[i], bf[j], acc[i][j], 0, 0, 0);
  }

#pragma unroll
  for (int j = 0; j < 4; ++j) {
    int colr = col0 + wc + j * 16 + l15;
    float bv = bias[colr];
#pragma unroll
    for (int i = 0; i < 4; ++i) {
#pragma unroll
      for (int r = 0; r < 4; ++r) {
        int rowr = row0 + wr + i * 16 + lhi * 4 + r;
        float val = acc[i][j][r] + bv;
        if constexpr (BF16_OUT)
          ((bf16_t*)Cv)[(size_t)rowr * N + colr] = (bf16_t)val;
        else
          ((float*)Cv)[(size_t)rowr * N + colr] = val;
      }
    }
  }
}

// ---------------------------------------------------------------------------
// Transpose V out of qkv_bf into Vg[bh][d][t] (bf16).
// ---------------------------------------------------------------------------
__global__ __launch_bounds__(256) void transpose_v(
    const bf16_t* __restrict__ qkv, bf16_t* __restrict__ Vg) {
  const int bh = blockIdx.y;
  const int b = bh >> 4, h = bh & 15;
  const int t0 = blockIdx.x * 64;
  const int tid = threadIdx.x;
  const int d = tid & 63;
  const int w = tid >> 6;
  alignas(16) bf16_t tmp[16];
#pragma unroll
  for (int j = 0; j < 16; ++j) {
    int t = t0 + w * 16 + j;
    tmp[j] = qkv[(size_t)(b * T_ + t) * D3_ + 2 * D_ + h * HD_ + d];
  }
  bf16_t* dst = Vg + (size_t)(bh * HD_ + d) * T_ + t0 + w * 16;
  *(uint4*)(dst) = *(const uint4*)(tmp);
  *(uint4*)(dst + 8) = *(const uint4*)(tmp + 8);
}

// ---------------------------------------------------------------------------
// Causal flash attention, swapped-QK^T 16x16x32 MFMA.
// Block = 4 waves, 128 q rows; wave w owns rows [Q0+32w, Q0+32w+32) as 2
// groups of 16. S^T = mfma(K_frag, Q_frag): lane l holds, for q=Q0+..+(l&15),
// keys n*16+(l>>4)*4+r -> lane-local softmax, 2 shfl_xor reduce, defer-max.
// K double-buffered + V single-buffered in LDS, staged by global_load_lds
// with 8-chunk XOR source-side swizzle (linear LDS dest, swizzled ds_read).
// ---------------------------------------------------------------------------
#define QBLK 128
#define KBLK 64

__global__ __launch_bounds__(256, 4) void attn_fwd_mfma(
    const bf16_t* __restrict__ qkv, const bf16_t* __restrict__ Vg,
    bf16_t* __restrict__ y) {
  const int lin = blockIdx.x;
  const int bh = (lin & 7) * 8 + ((lin >> 3) & 7);  // XCD-local heads
  const int qt = (T_ / QBLK - 1) - (lin >> 6);      // tail-first
  const int b = bh >> 4, h = bh & 15;
  const int Q0 = qt * QBLK;
  const int tid = threadIdx.x;
  const int w = tid >> 6, l = tid & 63;
  const int l15 = l & 15, lhi = l >> 4;

  __shared__ __align__(16) bf16_t K_lds[2][KBLK * 64];  // 16 KB, swizzled
  __shared__ __align__(16) bf16_t V_lds[KBLK * 64];     // 8 KB,  swizzled (rows=d)
  __shared__ __align__(16) bf16_t P_lds[4][16][72];     // 9 KB,  per-wave

  // staging source mapping (both rounds): row' = R*32 + sr, phys chunk sp,
  // logical d/t-chunk slc = sp ^ (row'&7) = sp ^ (sr&7)
  const int sr = tid >> 3, sp = tid & 7;
  const int slc = sp ^ (sr & 7);
  const int swz = (l15 & 7);  // read-side XOR

  auto stageK = [&](int buf, int kt) {
    const bf16_t* src =
        qkv + (size_t)(b * T_ + kt * KBLK + sr) * D3_ + D_ + h * HD_ + slc * 8;
    char* dst = (char*)(&K_lds[buf][0]) + w * 1024;
    load_lds16(src, dst);
    load_lds16(src + (size_t)32 * D3_, dst + 4096);
  };
  auto stageV = [&](int kt) {
    const bf16_t* src = Vg + ((size_t)bh * HD_ + sr) * T_ + kt * KBLK + slc * 8;
    char* dst = (char*)(&V_lds[0]) + w * 1024;
    load_lds16(src, dst);
    load_lds16(src + (size_t)32 * T_, dst + 4096);
  };

  // Q fragments, pre-scaled by 1/sqrt(64) (exact in bf16)
  bf16x8 qf[2][2];
#pragma unroll
  for (int g = 0; g < 2; ++g) {
    int q = Q0 + w * 32 + g * 16 + l15;
#pragma unroll
    for (int c = 0; c < 2; ++c) {
      const bf16_t* p = qkv + (size_t)(b * T_ + q) * D3_ + h * HD_ + c * 32 + lhi * 8;
      bf16x8 v = *(const bf16x8*)p;
#pragma unroll
      for (int e = 0; e < 8; ++e) v[e] = (bf16_t)((float)v[e] * 0.125f);
      qf[g][c] = v;
    }
  }

  f32x4 accO[2][4];
#pragma unroll
  for (int g = 0; g < 2; ++g)
#pragma unroll
    for (int dg = 0; dg < 4; ++dg) accO[g][dg] = (f32x4){0.f, 0.f, 0.f, 0.f};
  float m[2] = {-INFINITY, -INFINITY};
  float lsum[2] = {0.f, 0.f};

  const int ntiles = Q0 / KBLK + 2;
  const int qg0 = Q0 + w * 32;
  const int qg1 = qg0 + 16;

  stageK(0, 0);
  __syncthreads();

  for (int kt = 0; kt < ntiles; ++kt) {
    const int cur = kt & 1;
    const int ktb = kt * KBLK;
    stageV(kt);
    if (kt + 1 < ntiles) stageK(cur ^ 1, kt + 1);

    const bool act0 = (ktb <= qg0 + 15);
    const bool act1 = (ktb <= qg1 + 15);
    uint2 pp1[4];  // group-1 packed P (written to LDS after B1)

#pragma unroll
    for (int g = 0; g < 2; ++g) {
      if (!(g == 0 ? act0 : act1)) continue;
      const int qg = g == 0 ? qg0 : qg1;

      // ---- S^T = K·Q^T ----
      f32x4 s[4];
#pragma unroll
      for (int n = 0; n < 4; ++n) s[n] = (f32x4){0.f, 0.f, 0.f, 0.f};
#pragma unroll
      for (int c = 0; c < 2; ++c) {
#pragma unroll
        for (int n = 0; n < 4; ++n) {
          bf16x8 kf = *(const bf16x8*)&K_lds[cur][(n * 16 + l15) * 64 +
                                                 (((c * 4 + lhi) ^ swz) * 8)];
          s[n] = __builtin_amdgcn_mfma_f32_16x16x32_bf16(kf, qf[g][c], s[n], 0, 0, 0);
        }
      }

      // lane holds S^T[key = ktb+n*16+lhi*4+r][q = qg+l15]
      float sv[4][4];
#pragma unroll
      for (int n = 0; n < 4; ++n)
#pragma unroll
        for (int r = 0; r < 4; ++r) sv[n][r] = s[n][r];
      if (ktb + KBLK - 1 > qg) {  // diagonal tile: causal mask
        const int qml = qg + l15 - ktb - lhi * 4;
#pragma unroll
        for (int n = 0; n < 4; ++n)
#pragma unroll
          for (int r = 0; r < 4; ++r)
            if (n * 16 + r > qml) sv[n][r] = -INFINITY;
      }

      // ---- lane-local max + 2-step cross reduce ----
      float pm = sv[0][0];
#pragma unroll
      for (int n = 0; n < 4; ++n)
#pragma unroll
        for (int r = 0; r < 4; ++r) pm = fmaxf(pm, sv[n][r]);
      pm = fmaxf(pm, __shfl_xor(pm, 16));
      pm = fmaxf(pm, __shfl_xor(pm, 32));

      // ---- defer-max rescale ----
      if (!__all(pm <= m[g] + 8.f)) {
        float mn = fmaxf(m[g], pm);
        float corrq = __expf(m[g] - mn);
        m[g] = mn;
        lsum[g] *= corrq;
        float cr[4];
#pragma unroll
        for (int r = 0; r < 4; ++r) cr[r] = __shfl(corrq, lhi * 4 + r);
#pragma unroll
        for (int dg = 0; dg < 4; ++dg)
#pragma unroll
          for (int r = 0; r < 4; ++r) accO[g][dg][r] *= cr[r];
      }
      const float mn = m[g];

      // ---- exp, rowsum, pack P ----
      float rowsum = 0.f;
#pragma unroll
      for (int n = 0; n < 4; ++n) {
        alignas(8) bf16_t p4[4];
#pragma unroll
        for (int r = 0; r < 4; ++r) {
          float p = __expf(sv[n][r] - mn);
          rowsum += p;
          p4[r] = (bf16_t)p;
        }
        if (g == 0)
          *(uint2*)&P_lds[w][l15][n * 16 + lhi * 4] = *(const uint2*)p4;
        else
          pp1[n] = *(const uint2*)p4;
      }
      rowsum += __shfl_xor(rowsum, 16);
      rowsum += __shfl_xor(rowsum, 32);
      lsum[g] += rowsum;
    }

    __syncthreads();  // B1: V + K-prefetch landed; P(g0) visible to this wave

    if (act0) {
#pragma unroll
      for (int c2 = 0; c2 < 2; ++c2) {
        bf16x8 pf = *(const bf16x8*)&P_lds[w][l15][c2 * 32 + lhi * 8];
#pragma unroll
        for (int dg = 0; dg < 4; ++dg) {
          bf16x8 vf = *(const bf16x8*)&V_lds[(dg * 16 + l15) * 64 +
                                             (((c2 * 4 + lhi) ^ swz) * 8)];
          accO[0][dg] =
              __builtin_amdgcn_mfma_f32_16x16x32_bf16(pf, vf, accO[0][dg], 0, 0, 0);
        }
      }
    }
    if (act1) {
#pragma unroll
      for (int n = 0; n < 4; ++n)
        *(uint2*)&P_lds[w][l15][n * 16 + lhi * 4] = pp1[n];
#pragma unroll
      for (int c2 = 0; c2 < 2; ++c2) {
        bf16x8 pf = *(const bf16x8*)&P_lds[w][l15][c2 * 32 + lhi * 8];
#pragma unroll
        for (int dg = 0; dg < 4; ++dg) {
          bf16x8 vf = *(const bf16x8*)&V_lds[(dg * 16 + l15) * 64 +
                                             (((c2 * 4 + lhi) ^ swz) * 8)];
          accO[1][dg] =
              __builtin_amdgcn_mfma_f32_16x16x32_bf16(pf, vf, accO[1][dg], 0, 0, 0);
        }
      }
    }

    __syncthreads();  // B2: all reads of V / K[cur] done before restage
  }

  // epilogue: O/l -> y (bf16). accO: row(q)=lhi*4+r, col(d)=l15(+16dg)
#pragma unroll
  for (int g = 0; g < 2; ++g)
#pragma unroll
    for (int r = 0; r < 4; ++r) {
      float ls = __shfl(lsum[g], lhi * 4 + r);
      float inv = 1.f / ls;
      int q = Q0 + w * 32 + g * 16 + lhi * 4 + r;
      bf16_t* yr = y + (size_t)(b * T_ + q) * D_ + h * HD_ + l15;
#pragma unroll
      for (int dg = 0; dg < 4; ++dg) yr[dg * 16] = (bf16_t)(accO[g][dg][r] * inv);
    }
}

// ---------------------------------------------------------------------------
extern "C" void kernel_launch(void* const* d_in, const int* in_sizes, int n_in,
                              void* d_out, int out_size, void* d_ws, size_t ws_size,
                              hipStream_t stream) {
  const float* x      = (const float*)d_in[0];
  const float* w_attn = (const float*)d_in[1];
  const float* b_attn = (const float*)d_in[2];
  const float* w_proj = (const float*)d_in[3];
  const float* b_proj = (const float*)d_in[4];
  float* out = (float*)d_out;

  const int M = B_ * T_;  // 8192

  bf16_t* xb      = (bf16_t*)d_ws;                         // 16 MB (reused as y_bf)
  bf16_t* wattnT  = xb + (size_t)M * D_;                   // 6 MB
  bf16_t* wprojT  = wattnT + (size_t)D3_ * D_;             // 2 MB
  bf16_t* qkv_bf  = wprojT + (size_t)D_ * D_;              // 48 MB
  bf16_t* Vg      = qkv_bf + (size_t)M * D3_;              // 16 MB
  bf16_t* y_bf    = xb;

  convert_bf16<<<2048, 256, 0, stream>>>(x, xb, M * D_ / 4);
  transpose_convert<<<dim3(D_ / 64, D3_ / 64), 256, 0, stream>>>(w_attn, wattnT, D_, D3_);
  transpose_convert<<<dim3(D_ / 64, D_ / 64), 256, 0, stream>>>(w_proj, wprojT, D_, D_);
  gemm_bt_mfma<true><<<dim3(D3_ / GBN, M / GBM), 256, 0, stream>>>(
      xb, wattnT, b_attn, qkv_bf, M, D3_, D_);
  transpose_v<<<dim3(T_ / 64, B_ * H_), 256, 0, stream>>>(qkv_bf, Vg);
  attn_fwd_mfma<<<dim3(T_ / QBLK * B_ * H_), 256, 0, stream>>>(qkv_bf, Vg, y_bf);
  gemm_bt_mfma<false><<<dim3(D_ / GBN, M / GBM), 256, 0, stream>>>(
      y_bf, wprojT, b_proj, out, M, D_, D_);
}

// Round 5
// 190.253 us; speedup vs baseline: 13.7417x; 1.0397x over previous
//
#include <hip/hip_runtime.h>
#include <math.h>

typedef __bf16 bf16_t;
typedef __attribute__((ext_vector_type(8))) __bf16 bf16x8;
typedef __attribute__((ext_vector_type(4))) float f32x4;

#define B_  4
#define T_  2048
#define D_  1024
#define H_  16
#define HD_ 64
#define D3_ 3072

__device__ __forceinline__ void load_lds16(const bf16_t* g, char* lds) {
  __builtin_amdgcn_global_load_lds(
      (const __attribute__((address_space(1))) void*)g,
      (__attribute__((address_space(3))) void*)lds, 16, 0, 0);
}

// ---------------------------------------------------------------------------
// fp32 -> bf16 elementwise convert (vectorized)
// ---------------------------------------------------------------------------
__global__ __launch_bounds__(256) void convert_bf16(
    const float* __restrict__ in, bf16_t* __restrict__ out, int n4) {
  int idx = blockIdx.x * 256 + threadIdx.x;
  int stride = gridDim.x * 256;
  for (int i = idx; i < n4; i += stride) {
    float4 v = ((const float4*)in)[i];
    alignas(8) bf16_t o4[4] = {(bf16_t)v.x, (bf16_t)v.y, (bf16_t)v.z, (bf16_t)v.w};
    ((uint2*)out)[i] = *(const uint2*)o4;
  }
}

// ---------------------------------------------------------------------------
// W (K x N fp32) -> Wt (N x K bf16), tiled 64x64 transpose through LDS.
// ---------------------------------------------------------------------------
__global__ __launch_bounds__(256) void transpose_convert(
    const float* __restrict__ W, bf16_t* __restrict__ Wt, int K, int N) {
  __shared__ float tile[64][65];
  const int k0 = blockIdx.x * 64, n0 = blockIdx.y * 64;
  const int tid = threadIdx.x;
  const int r = tid >> 4, c4 = (tid & 15) * 4;
#pragma unroll
  for (int i = 0; i < 4; ++i) {
    float4 v = *(const float4*)(W + (size_t)(k0 + r + i * 16) * N + n0 + c4);
    tile[r + i * 16][c4 + 0] = v.x;
    tile[r + i * 16][c4 + 1] = v.y;
    tile[r + i * 16][c4 + 2] = v.z;
    tile[r + i * 16][c4 + 3] = v.w;
  }
  __syncthreads();
#pragma unroll
  for (int i = 0; i < 4; ++i) {
    int n = r + i * 16;
    alignas(8) bf16_t o4[4];
#pragma unroll
    for (int j = 0; j < 4; ++j) o4[j] = (bf16_t)tile[c4 + j][n];
    *(uint2*)(Wt + (size_t)(n0 + n) * K + k0 + c4) = *(const uint2*)o4;
  }
}

// ---------------------------------------------------------------------------
// bf16 MFMA GEMM: C[M][N] = A[M][K] @ Bt[N][K]^T + bias[N]
// 128x128 tile, BK=32, 4 waves, 4x4 16x16x32 frags. v2: double-buffered LDS
// 2-phase pipeline (T3-min): stage tile t+1 right after the single loop-top
// barrier; drain happens at the NEXT iteration's barrier, so loads hide under
// the 16-MFMA compute phase. Source-chunk XOR swizzle unchanged (proven).
// ---------------------------------------------------------------------------
#define GBM 128
#define GBN 128
#define GBK 32

template <bool BF16_OUT>
__global__ __launch_bounds__(256) void gemm_bt_mfma(
    const bf16_t* __restrict__ A, const bf16_t* __restrict__ Bt,
    const float* __restrict__ bias, void* __restrict__ Cv,
    int M, int N, int K) {
  __shared__ __align__(16) bf16_t Asl[2][GBM * GBK];  // 2 x 8 KB
  __shared__ __align__(16) bf16_t Bsl[2][GBN * GBK];  // 2 x 8 KB

  const int tid = threadIdx.x;
  const int w = tid >> 6, l = tid & 63;
  const int l15 = l & 15, lhi = l >> 4;
  const int row0 = blockIdx.y * GBM, col0 = blockIdx.x * GBN;
  const int wr = (w >> 1) * 64, wc = (w & 1) * 64;

  const int srow = tid >> 2;
  const int sf = (srow & 3) ^ ((srow >> 2) & 3);
  const int slog = (tid & 3) ^ sf;
  const int rf = (l15 & 3) ^ ((l15 >> 2) & 3);
  const int rchunk = lhi ^ rf;

  f32x4 acc[4][4];
#pragma unroll
  for (int i = 0; i < 4; ++i)
#pragma unroll
    for (int j = 0; j < 4; ++j) acc[i][j] = (f32x4){0.f, 0.f, 0.f, 0.f};

  const bf16_t* Abase = A + (size_t)row0 * K;
  const bf16_t* Bbase = Bt + (size_t)col0 * K;

  auto stage = [&](int buf, int k0) {
#pragma unroll
    for (int issue = 0; issue < 2; ++issue) {
      const bf16_t* ga = Abase + (size_t)(issue * 64 + srow) * K + k0 + slog * 8;
      load_lds16(ga, (char*)&Asl[buf][0] + issue * 4096 + w * 1024);
      const bf16_t* gb = Bbase + (size_t)(issue * 64 + srow) * K + k0 + slog * 8;
      load_lds16(gb, (char*)&Bsl[buf][0] + issue * 4096 + w * 1024);
    }
  };

  const int nt = K / GBK;
  stage(0, 0);

  for (int t = 0; t < nt; ++t) {
    __syncthreads();  // drains tile-t loads (issued last iter, overlapped);
                      // also: all waves done reading buf[(t+1)&1] from t-1
    if (t + 1 < nt) stage((t + 1) & 1, (t + 1) * GBK);

    const bf16_t* As = &Asl[t & 1][0];
    const bf16_t* Bs = &Bsl[t & 1][0];
    bf16x8 af[4], bf[4];
#pragma unroll
    for (int i = 0; i < 4; ++i)
      af[i] = *(const bf16x8*)&As[(wr + i * 16 + l15) * GBK + rchunk * 8];
#pragma unroll
    for (int j = 0; j < 4; ++j)
      bf[j] = *(const bf16x8*)&Bs[(wc + j * 16 + l15) * GBK + rchunk * 8];
#pragma unroll
    for (int i = 0; i < 4; ++i)
#pragma unroll
      for (int j = 0; j < 4; ++j)
        acc[i][j] =
            __builtin_amdgcn_mfma_f32_16x16x32_bf16(af[i], bf[j], acc[i][j], 0, 0, 0);
  }

  // epilogue: C/D layout col=l&15, row=(l>>4)*4+reg
#pragma unroll
  for (int j = 0; j < 4; ++j) {
    int colr = col0 + wc + j * 16 + l15;
    float bv = bias[colr];
#pragma unroll
    for (int i = 0; i < 4; ++i) {
#pragma unroll
      for (int r = 0; r < 4; ++r) {
        int rowr = row0 + wr + i * 16 + lhi * 4 + r;
        float val = acc[i][j][r] + bv;
        if constexpr (BF16_OUT)
          ((bf16_t*)Cv)[(size_t)rowr * N + colr] = (bf16_t)val;
        else
          ((float*)Cv)[(size_t)rowr * N + colr] = val;
      }
    }
  }
}

// ---------------------------------------------------------------------------
// Transpose V out of qkv_bf into Vg[bh][d][t] (bf16).
// ---------------------------------------------------------------------------
__global__ __launch_bounds__(256) void transpose_v(
    const bf16_t* __restrict__ qkv, bf16_t* __restrict__ Vg) {
  const int bh = blockIdx.y;
  const int b = bh >> 4, h = bh & 15;
  const int t0 = blockIdx.x * 64;
  const int tid = threadIdx.x;
  const int d = tid & 63;
  const int w = tid >> 6;
  alignas(16) bf16_t tmp[16];
#pragma unroll
  for (int j = 0; j < 16; ++j) {
    int t = t0 + w * 16 + j;
    tmp[j] = qkv[(size_t)(b * T_ + t) * D3_ + 2 * D_ + h * HD_ + d];
  }
  bf16_t* dst = Vg + (size_t)(bh * HD_ + d) * T_ + t0 + w * 16;
  *(uint4*)(dst) = *(const uint4*)(tmp);
  *(uint4*)(dst + 8) = *(const uint4*)(tmp + 8);
}

// ---------------------------------------------------------------------------
// Causal flash attention, swapped-QK^T 16x16x32 MFMA.  (unchanged from R4)
// ---------------------------------------------------------------------------
#define QBLK 128
#define KBLK 64

__global__ __launch_bounds__(256, 4) void attn_fwd_mfma(
    const bf16_t* __restrict__ qkv, const bf16_t* __restrict__ Vg,
    bf16_t* __restrict__ y) {
  const int lin = blockIdx.x;
  const int bh = (lin & 7) * 8 + ((lin >> 3) & 7);  // XCD-local heads
  const int qt = (T_ / QBLK - 1) - (lin >> 6);      // tail-first
  const int b = bh >> 4, h = bh & 15;
  const int Q0 = qt * QBLK;
  const int tid = threadIdx.x;
  const int w = tid >> 6, l = tid & 63;
  const int l15 = l & 15, lhi = l >> 4;

  __shared__ __align__(16) bf16_t K_lds[2][KBLK * 64];  // 16 KB, swizzled
  __shared__ __align__(16) bf16_t V_lds[KBLK * 64];     // 8 KB,  swizzled (rows=d)
  __shared__ __align__(16) bf16_t P_lds[4][16][72];     // 9 KB,  per-wave

  const int sr = tid >> 3, sp = tid & 7;
  const int slc = sp ^ (sr & 7);
  const int swz = (l15 & 7);  // read-side XOR

  auto stageK = [&](int buf, int kt) {
    const bf16_t* src =
        qkv + (size_t)(b * T_ + kt * KBLK + sr) * D3_ + D_ + h * HD_ + slc * 8;
    char* dst = (char*)(&K_lds[buf][0]) + w * 1024;
    load_lds16(src, dst);
    load_lds16(src + (size_t)32 * D3_, dst + 4096);
  };
  auto stageV = [&](int kt) {
    const bf16_t* src = Vg + ((size_t)bh * HD_ + sr) * T_ + kt * KBLK + slc * 8;
    char* dst = (char*)(&V_lds[0]) + w * 1024;
    load_lds16(src, dst);
    load_lds16(src + (size_t)32 * T_, dst + 4096);
  };

  // Q fragments, pre-scaled by 1/sqrt(64) (exact in bf16)
  bf16x8 qf[2][2];
#pragma unroll
  for (int g = 0; g < 2; ++g) {
    int q = Q0 + w * 32 + g * 16 + l15;
#pragma unroll
    for (int c = 0; c < 2; ++c) {
      const bf16_t* p = qkv + (size_t)(b * T_ + q) * D3_ + h * HD_ + c * 32 + lhi * 8;
      bf16x8 v = *(const bf16x8*)p;
#pragma unroll
      for (int e = 0; e < 8; ++e) v[e] = (bf16_t)((float)v[e] * 0.125f);
      qf[g][c] = v;
    }
  }

  f32x4 accO[2][4];
#pragma unroll
  for (int g = 0; g < 2; ++g)
#pragma unroll
    for (int dg = 0; dg < 4; ++dg) accO[g][dg] = (f32x4){0.f, 0.f, 0.f, 0.f};
  float m[2] = {-INFINITY, -INFINITY};
  float lsum[2] = {0.f, 0.f};

  const int ntiles = Q0 / KBLK + 2;
  const int qg0 = Q0 + w * 32;
  const int qg1 = qg0 + 16;

  stageK(0, 0);
  __syncthreads();

  for (int kt = 0; kt < ntiles; ++kt) {
    const int cur = kt & 1;
    const int ktb = kt * KBLK;
    stageV(kt);
    if (kt + 1 < ntiles) stageK(cur ^ 1, kt + 1);

    const bool act0 = (ktb <= qg0 + 15);
    const bool act1 = (ktb <= qg1 + 15);
    uint2 pp1[4];  // group-1 packed P (written to LDS after B1)

#pragma unroll
    for (int g = 0; g < 2; ++g) {
      if (!(g == 0 ? act0 : act1)) continue;
      const int qg = g == 0 ? qg0 : qg1;

      // ---- S^T = K·Q^T ----
      f32x4 s[4];
#pragma unroll
      for (int n = 0; n < 4; ++n) s[n] = (f32x4){0.f, 0.f, 0.f, 0.f};
#pragma unroll
      for (int c = 0; c < 2; ++c) {
#pragma unroll
        for (int n = 0; n < 4; ++n) {
          bf16x8 kf = *(const bf16x8*)&K_lds[cur][(n * 16 + l15) * 64 +
                                                 (((c * 4 + lhi) ^ swz) * 8)];
          s[n] = __builtin_amdgcn_mfma_f32_16x16x32_bf16(kf, qf[g][c], s[n], 0, 0, 0);
        }
      }

      // lane holds S^T[key = ktb+n*16+lhi*4+r][q = qg+l15]
      float sv[4][4];
#pragma unroll
      for (int n = 0; n < 4; ++n)
#pragma unroll
        for (int r = 0; r < 4; ++r) sv[n][r] = s[n][r];
      if (ktb + KBLK - 1 > qg) {  // diagonal tile: causal mask
        const int qml = qg + l15 - ktb - lhi * 4;
#pragma unroll
        for (int n = 0; n < 4; ++n)
#pragma unroll
          for (int r = 0; r < 4; ++r)
            if (n * 16 + r > qml) sv[n][r] = -INFINITY;
      }

      // ---- lane-local max + 2-step cross reduce ----
      float pm = sv[0][0];
#pragma unroll
      for (int n = 0; n < 4; ++n)
#pragma unroll
        for (int r = 0; r < 4; ++r) pm = fmaxf(pm, sv[n][r]);
      pm = fmaxf(pm, __shfl_xor(pm, 16));
      pm = fmaxf(pm, __shfl_xor(pm, 32));

      // ---- defer-max rescale ----
      if (!__all(pm <= m[g] + 8.f)) {
        float mn = fmaxf(m[g], pm);
        float corrq = __expf(m[g] - mn);
        m[g] = mn;
        lsum[g] *= corrq;
        float cr[4];
#pragma unroll
        for (int r = 0; r < 4; ++r) cr[r] = __shfl(corrq, lhi * 4 + r);
#pragma unroll
        for (int dg = 0; dg < 4; ++dg)
#pragma unroll
          for (int r = 0; r < 4; ++r) accO[g][dg][r] *= cr[r];
      }
      const float mn = m[g];

      // ---- exp, rowsum, pack P ----
      float rowsum = 0.f;
#pragma unroll
      for (int n = 0; n < 4; ++n) {
        alignas(8) bf16_t p4[4];
#pragma unroll
        for (int r = 0; r < 4; ++r) {
          float p = __expf(sv[n][r] - mn);
          rowsum += p;
          p4[r] = (bf16_t)p;
        }
        if (g == 0)
          *(uint2*)&P_lds[w][l15][n * 16 + lhi * 4] = *(const uint2*)p4;
        else
          pp1[n] = *(const uint2*)p4;
      }
      rowsum += __shfl_xor(rowsum, 16);
      rowsum += __shfl_xor(rowsum, 32);
      lsum[g] += rowsum;
    }

    __syncthreads();  // B1: V + K-prefetch landed; P(g0) visible to this wave

    if (act0) {
#pragma unroll
      for (int c2 = 0; c2 < 2; ++c2) {
        bf16x8 pf = *(const bf16x8*)&P_lds[w][l15][c2 * 32 + lhi * 8];
#pragma unroll
        for (int dg = 0; dg < 4; ++dg) {
          bf16x8 vf = *(const bf16x8*)&V_lds[(dg * 16 + l15) * 64 +
                                             (((c2 * 4 + lhi) ^ swz) * 8)];
          accO[0][dg] =
              __builtin_amdgcn_mfma_f32_16x16x32_bf16(pf, vf, accO[0][dg], 0, 0, 0);
        }
      }
    }
    if (act1) {
#pragma unroll
      for (int n = 0; n < 4; ++n)
        *(uint2*)&P_lds[w][l15][n * 16 + lhi * 4] = pp1[n];
#pragma unroll
      for (int c2 = 0; c2 < 2; ++c2) {
        bf16x8 pf = *(const bf16x8*)&P_lds[w][l15][c2 * 32 + lhi * 8];
#pragma unroll
        for (int dg = 0; dg < 4; ++dg) {
          bf16x8 vf = *(const bf16x8*)&V_lds[(dg * 16 + l15) * 64 +
                                             (((c2 * 4 + lhi) ^ swz) * 8)];
          accO[1][dg] =
              __builtin_amdgcn_mfma_f32_16x16x32_bf16(pf, vf, accO[1][dg], 0, 0, 0);
        }
      }
    }

    __syncthreads();  // B2: all reads of V / K[cur] done before restage
  }

  // epilogue: O/l -> y (bf16). accO: row(q)=lhi*4+r, col(d)=l15(+16dg)
#pragma unroll
  for (int g = 0; g < 2; ++g)
#pragma unroll
    for (int r = 0; r < 4; ++r) {
      float ls = __shfl(lsum[g], lhi * 4 + r);
      float inv = 1.f / ls;
      int q = Q0 + w * 32 + g * 16 + lhi * 4 + r;
      bf16_t* yr = y + (size_t)(b * T_ + q) * D_ + h * HD_ + l15;
#pragma unroll
      for (int dg = 0; dg < 4; ++dg) yr[dg * 16] = (bf16_t)(accO[g][dg][r] * inv);
    }
}

// ---------------------------------------------------------------------------
extern "C" void kernel_launch(void* const* d_in, const int* in_sizes, int n_in,
                              void* d_out, int out_size, void* d_ws, size_t ws_size,
                              hipStream_t stream) {
  const float* x      = (const float*)d_in[0];
  const float* w_attn = (const float*)d_in[1];
  const float* b_attn = (const float*)d_in[2];
  const float* w_proj = (const float*)d_in[3];
  const float* b_proj = (const float*)d_in[4];
  float* out = (float*)d_out;

  const int M = B_ * T_;  // 8192

  bf16_t* xb      = (bf16_t*)d_ws;                         // 16 MB (reused as y_bf)
  bf16_t* wattnT  = xb + (size_t)M * D_;                   // 6 MB
  bf16_t* wprojT  = wattnT + (size_t)D3_ * D_;             // 2 MB
  bf16_t* qkv_bf  = wprojT + (size_t)D_ * D_;              // 48 MB
  bf16_t* Vg      = qkv_bf + (size_t)M * D3_;              // 16 MB
  bf16_t* y_bf    = xb;

  convert_bf16<<<2048, 256, 0, stream>>>(x, xb, M * D_ / 4);
  transpose_convert<<<dim3(D_ / 64, D3_ / 64), 256, 0, stream>>>(w_attn, wattnT, D_, D3_);
  transpose_convert<<<dim3(D_ / 64, D_ / 64), 256, 0, stream>>>(w_proj, wprojT, D_, D_);
  gemm_bt_mfma<true><<<dim3(D3_ / GBN, M / GBM), 256, 0, stream>>>(
      xb, wattnT, b_attn, qkv_bf, M, D3_, D_);
  transpose_v<<<dim3(T_ / 64, B_ * H_), 256, 0, stream>>>(qkv_bf, Vg);
  attn_fwd_mfma<<<dim3(T_ / QBLK * B_ * H_), 256, 0, stream>>>(qkv_bf, Vg, y_bf);
  gemm_bt_mfma<false><<<dim3(D_ / GBN, M / GBM), 256, 0, stream>>>(
      y_bf, wprojT, b_proj, out, M, D_, D_);
}